// Round 7
// baseline (466.735 us; speedup 1.0000x reference)
//
#include <hip/hip_runtime.h>

typedef short short8 __attribute__((ext_vector_type(8)));
typedef float floatx4 __attribute__((ext_vector_type(4)));

#define BB   8
#define CIN  16
#define COUT 32
#define DD   64
#define NUM_W (CIN * COUT * 27)   // 13824
#define NUM_P (NUM_W + COUT)      // 13856
#define KPAD  448                 // 28 taps * 16 ci (tap 27 = zeros)

// ws layout (floats): [0,64) h1 (8x8); [64,320) bias (8x32);
// [320, ...) A_bf16 as shorts: 8*32*448 shorts = 229376 B. Total ~231 KB.

__device__ __forceinline__ short f2bf(float f) {
    union { float f; unsigned u; } v; v.f = f;
    unsigned r = v.u + 0x7FFF + ((v.u >> 16) & 1);   // RNE
    return (short)(r >> 16);
}

// pack bf16(lo) | bf16(hi)<<16, both RNE — identical numerics to f2bf
__device__ __forceinline__ unsigned pack2bf(float lo, float hi) {
    union { float f; unsigned u; } a, b; a.f = lo; b.f = hi;
    unsigned ra = a.u + 0x7FFF + ((a.u >> 16) & 1);
    unsigned rb = b.u + 0x7FFF + ((b.u >> 16) & 1);
    return (ra >> 16) | (rb & 0xFFFF0000u);
}

// LDS bank-conflict swizzle for the x-patch: XOR bits 4-6 with bits 7-9.
// Bijective per 128B window (xs = 38016 B = 297 * 128B exactly).
__device__ __forceinline__ int swz(int byte) {
    return byte ^ (((byte >> 7) & 7) << 4);
}

__global__ void hyper_kernel(const float* __restrict__ features,
                             const float* __restrict__ fc0_w,
                             const float* __restrict__ fc0_b,
                             const float* __restrict__ a0,
                             const float* __restrict__ fc1_w,
                             const float* __restrict__ fc1_b,
                             const float* __restrict__ a1,
                             const float* __restrict__ wg_w,
                             const float* __restrict__ wg_b,
                             float* __restrict__ h1out,
                             float* __restrict__ biasout) {
    __shared__ float h0[8][16];
    __shared__ float h1s[8][8];
    const int t = threadIdx.x;  // 256
    if (t < 128) {
        const int b = t >> 4, i = t & 15;
        float s = fc0_b[i];
        #pragma unroll
        for (int j = 0; j < 10; ++j) s += features[b * 10 + j] * fc0_w[i * 10 + j];
        const float a = a0[0];
        h0[b][i] = (s >= 0.f) ? s : a * s;
    }
    __syncthreads();
    if (t < 64) {
        const int b = t >> 3, i = t & 7;
        float s = fc1_b[i];
        #pragma unroll
        for (int j = 0; j < 16; ++j) s += h0[b][j] * fc1_w[i * 16 + j];
        const float a = a1[0];
        const float r = (s >= 0.f) ? s : a * s;
        h1s[b][i] = r;
        h1out[b * 8 + i] = r;
    }
    __syncthreads();
    {   // biases: 256 threads = 8 b x 32 co
        const int b = t >> 5, co = t & 31;
        const int p = NUM_W + co;
        float s = wg_b[p];
        #pragma unroll
        for (int j = 0; j < 8; ++j) s += h1s[b][j] * wg_w[p * 8 + j];
        biasout[b * 32 + co] = s;
    }
}

// A_bf16[b][co][k], k = tap*16 + ci, tap = kd*9+kh*3+kw, zero for tap==27
__global__ void wgen_kernel(const float* __restrict__ h1,
                            const float* __restrict__ wg_w,
                            const float* __restrict__ wg_b,
                            short* __restrict__ A) {
    const int b  = blockIdx.y;
    const int id = blockIdx.x * 256 + threadIdx.x;  // [0, 32*16*28)
    const int tap  = id % 28;
    const int rest = id / 28;        // co*16 + ci
    const int ci   = rest & 15;
    const int co   = rest >> 4;
    float val = 0.f;
    if (tap < 27) {
        const int p = co * 432 + ci * 27 + tap;
        float s = wg_b[p];
        #pragma unroll
        for (int j = 0; j < 8; ++j) s += h1[b * 8 + j] * wg_w[p * 8 + j];
        val = s;
    }
    A[(b * 32 + co) * KPAD + tap * 16 + ci] = f2bf(val);
}

// stage one (dz, phys-hz) row of the x-patch: 2 ci planes x float4 of w.
__device__ __forceinline__ void stage_one(const float* __restrict__ x, char* xsb,
                                          int b, int cp, int w4,
                                          int dz, int phys, int zd, int zh) {
    float4 v0 = {0.f, 0.f, 0.f, 0.f};
    float4 v1 = {0.f, 0.f, 0.f, 0.f};
    if (zd >= 0 && zd < DD && zh >= 0 && zh < DD) {   // wave-uniform
        const size_t gbase =
            (((size_t)(b * CIN + 2 * cp) * DD + zd) * DD + zh) * DD + w4;
        v0 = *(const float4*)(x + gbase);
        v1 = *(const float4*)(x + gbase + (size_t)DD * DD * DD);
    }
    const int rb = ((dz * 6 + phys) * 66 + (w4 + 1)) * 32 + 4 * cp;
    *(unsigned*)(xsb + swz(rb))      = pack2bf(v0.x, v1.x);
    *(unsigned*)(xsb + swz(rb + 32)) = pack2bf(v0.y, v1.y);
    *(unsigned*)(xsb + swz(rb + 64)) = pack2bf(v0.z, v1.z);
    *(unsigned*)(xsb + swz(rb + 96)) = pack2bf(v0.w, v1.w);
}

// Implicit-GEMM conv via MFMA 16x16x32 bf16 — persistent 8-tile blocks.
// Block = 256 thr = 4 waves; fixes (b, d, h-half); loops 8 tiles over h0.
// A (28 KB/sample) preloaded to VGPRs ONCE per block — waves_per_eu(2,2)
// grants the full 256-VGPR budget (8 waves/CU is the LDS-bound occupancy
// anyway), avoiding round-3's 128-clamp spill. K-loop LDS reads = x only.
// x-patch is a ROLLING hz-window (slot = (zh+1) mod 6): tiles 1..7 stage
// only the 12 new rows. LDS = 38 KB (x-window only).
__global__ __attribute__((amdgpu_flat_work_group_size(256, 256),
                          amdgpu_waves_per_eu(2, 2)))
void conv_mfma_kernel(
        const float* __restrict__ x,
        const short* __restrict__ A,
        const float* __restrict__ bias,
        float* __restrict__ out) {
    __shared__ uint4 xs4[2376];            // 38016 B: [dz 3][slot 6][wz 66][ci 16]
    char* xsb = (char*)xs4;

    const int t    = threadIdx.x;
    const int lane = t & 63;
    const int wave = t >> 6;
    const int n16  = lane & 15;
    const int q    = lane >> 4;

    // Persistent grid: 1024 blocks, 8 XCDs -> each XCD owns one sample b.
    const int lin   = blockIdx.x;                    // 0..1023
    const int o     = (lin & 7) * 128 + (lin >> 3);  // bijective
    const int b     = o >> 7;                        // 0..7
    const int rest  = o & 127;
    const int d     = rest >> 1;                     // 0..63
    const int hbase = (rest & 1) * 32;               // h0 = hbase + it*4

    const short* Ab = A + (size_t)(b * 32) * KPAD;

    // ---- preload ALL A-fragments once (112 VGPRs, live across tile loop) ----
    short8 afrag[14][2];
    #pragma unroll
    for (int c = 0; c < 14; ++c)
        #pragma unroll
        for (int mt = 0; mt < 2; ++mt)
            afrag[c][mt] = *(const short8*)(Ab + (mt * 16 + n16) * KPAD + c * 32 + q * 8);

    // ---- zero the w-halo columns (wz=0,65) once; staging never writes them ----
    if (t < 72) {
        const int rowl = t >> 2;                 // 0..17
        const int wz   = ((t >> 1) & 1) * 65;    // 0 or 65
        const int half = t & 1;
        const uint4 z4 = {0u, 0u, 0u, 0u};
        *(uint4*)(xsb + swz((rowl * 66 + wz) * 32 + half * 16)) = z4;
    }

    const float bv0 = bias[b * 32 + n16];
    const float bv1 = bias[b * 32 + 16 + n16];

    // staging thread map: (ci-pair cp, row-half rhalf)
    const int tid16 = wave * 4 + q;      // 0..15
    const int cp    = tid16 & 7;         // ci = 2*cp, 2*cp+1
    const int rhalf = tid16 >> 3;        // 0/1
    const int w4    = n16 * 4;

    const int ci_base2 = (q & 1) * 16;   // byte offset of ci half
    const int qh       = q >> 1;

    #pragma unroll 1
    for (int it = 0; it < 8; ++it) {
        const int h0 = hbase + it * 4;
        const int p  = h0 % 6;           // phys slot = (p + hz) mod 6 = (zh+1) mod 6

        __syncthreads();   // prev tile's LDS reads (or halo-zero) done

        if (it == 0) {
            // full window: 18 rows, 9 per rhalf
            #pragma unroll
            for (int i = 0; i < 9; ++i) {
                const int rowl = rhalf * 9 + i;          // dz*6+hz
                const int dz = rowl / 6, hz = rowl % 6;
                int phys = p + hz; if (phys >= 6) phys -= 6;
                stage_one(x, xsb, b, cp, w4, dz, phys, d + dz - 1, h0 + hz - 1);
            }
        } else {
            // rolling: only hz 2..5 are new (zh = h0+1 .. h0+4), 12 rows
            #pragma unroll
            for (int i = 0; i < 6; ++i) {
                const int idx = rhalf * 6 + i;           // 0..11
                const int dz = idx >> 2, j = idx & 3;    // hz = 2+j
                int phys = p + 2 + j; if (phys >= 6) phys -= 6;
                stage_one(x, xsb, b, cp, w4, dz, phys, d + dz - 1, h0 + 1 + j);
            }
        }
        __syncthreads();

        // ---- K-loop: operand-swapped MFMA (x in A slot, weights in B slot) ----
        floatx4 acc[2][4];
        #pragma unroll
        for (int mt = 0; mt < 2; ++mt)
            #pragma unroll
            for (int nt = 0; nt < 4; ++nt) acc[mt][nt] = (floatx4){0.f, 0.f, 0.f, 0.f};

        __builtin_amdgcn_s_setprio(1);
        #pragma unroll
        for (int c = 0; c < 14; ++c) {
            int tap = 2 * c + qh;
            if (tap > 26) tap = 26;        // A zero for k>=432, x value irrelevant
            const int kd = tap / 9;
            const int r  = tap - kd * 9;
            const int kh = r / 3;
            const int kw = r - kh * 3;
            int prow = p + wave + kh; if (prow >= 6) prow -= 6;
            const int rowb = ((kd * 6 + prow) * 66 + kw) * 32 + ci_base2;
            #pragma unroll
            for (int nt = 0; nt < 4; ++nt) {
                const short8 xf = *(const short8*)(xsb + swz(rowb + (nt * 16 + n16) * 32));
                acc[0][nt] = __builtin_amdgcn_mfma_f32_16x16x32_bf16(
                                 xf, afrag[c][0], acc[0][nt], 0, 0, 0);
                acc[1][nt] = __builtin_amdgcn_mfma_f32_16x16x32_bf16(
                                 xf, afrag[c][1], acc[1][nt], 0, 0, 0);
            }
        }
        __builtin_amdgcn_s_setprio(0);

        // ---- epilogue: row=w=nt*16+q*4+reg, col=co=mt*16+n16 -> float4 stores ----
        const int hh = h0 + wave;
        #pragma unroll
        for (int mt = 0; mt < 2; ++mt) {
            const float bv = mt ? bv1 : bv0;
            #pragma unroll
            for (int nt = 0; nt < 4; ++nt) {
                floatx4 rr = acc[mt][nt];
                rr[0] += bv; rr[1] += bv; rr[2] += bv; rr[3] += bv;
                *(floatx4*)(out + (((size_t)(b * COUT + mt * 16 + n16) * DD + d) * DD + hh) * DD
                                 + nt * 16 + q * 4) = rr;
            }
        }
    }
}

extern "C" void kernel_launch(void* const* d_in, const int* in_sizes, int n_in,
                              void* d_out, int out_size, void* d_ws, size_t ws_size,
                              hipStream_t stream) {
    const float* x        = (const float*)d_in[0];
    const float* features = (const float*)d_in[1];
    const float* fc0_w    = (const float*)d_in[2];
    const float* fc0_b    = (const float*)d_in[3];
    const float* a0       = (const float*)d_in[4];
    const float* fc1_w    = (const float*)d_in[5];
    const float* fc1_b    = (const float*)d_in[6];
    const float* a1       = (const float*)d_in[7];
    const float* wg_w     = (const float*)d_in[8];
    const float* wg_b     = (const float*)d_in[9];

    float* ws    = (float*)d_ws;
    float* h1    = ws;                // 64 floats
    float* biasp = ws + 64;           // 256 floats
    short* A     = (short*)(ws + 320);  // 8*32*448 shorts

    hyper_kernel<<<1, 256, 0, stream>>>(features, fc0_w, fc0_b, a0,
                                        fc1_w, fc1_b, a1, wg_w, wg_b, h1, biasp);
    wgen_kernel<<<dim3(56, BB), 256, 0, stream>>>(h1, wg_w, wg_b, A);
    conv_mfma_kernel<<<dim3(1024), 256, 0, stream>>>(x, A, biasp, (float*)d_out);
}

// Round 8
// 426.666 us; speedup vs baseline: 1.0939x; 1.0939x over previous
//
#include <hip/hip_runtime.h>

typedef short short8 __attribute__((ext_vector_type(8)));
typedef float floatx4 __attribute__((ext_vector_type(4)));

#define BB   8
#define CIN  16
#define COUT 32
#define DD   64
#define NUM_W (CIN * COUT * 27)   // 13824
#define NUM_P (NUM_W + COUT)      // 13856

// ws layout (floats): [0,64) h1 (8x8); [64,320) bias (8x32);
// [320, ...) A fragment-order bf16: AF[b][c 14][mt 2][lane 64][8 shorts]
//            = 8 * 14*2*64*8 shorts = 229376 B. Total ~231 KB.

__device__ __forceinline__ short f2bf(float f) {
    union { float f; unsigned u; } v; v.f = f;
    unsigned r = v.u + 0x7FFF + ((v.u >> 16) & 1);   // RNE
    return (short)(r >> 16);
}

// pack bf16(lo) | bf16(hi)<<16, both RNE — identical numerics to f2bf
__device__ __forceinline__ unsigned pack2bf(float lo, float hi) {
    union { float f; unsigned u; } a, b; a.f = lo; b.f = hi;
    unsigned ra = a.u + 0x7FFF + ((a.u >> 16) & 1);
    unsigned rb = b.u + 0x7FFF + ((b.u >> 16) & 1);
    return (ra >> 16) | (rb & 0xFFFF0000u);
}

// LDS bank-conflict swizzle for the x-patch: XOR bits 4-6 with bits 7-9.
// Bijective per 128B window (xs = 38016 B = 297 * 128B exactly).
__device__ __forceinline__ int swz(int byte) {
    return byte ^ (((byte >> 7) & 7) << 4);
}

__global__ void hyper_kernel(const float* __restrict__ features,
                             const float* __restrict__ fc0_w,
                             const float* __restrict__ fc0_b,
                             const float* __restrict__ a0,
                             const float* __restrict__ fc1_w,
                             const float* __restrict__ fc1_b,
                             const float* __restrict__ a1,
                             const float* __restrict__ wg_w,
                             const float* __restrict__ wg_b,
                             float* __restrict__ h1out,
                             float* __restrict__ biasout) {
    __shared__ float h0[8][16];
    __shared__ float h1s[8][8];
    const int t = threadIdx.x;  // 256
    if (t < 128) {
        const int b = t >> 4, i = t & 15;
        float s = fc0_b[i];
        #pragma unroll
        for (int j = 0; j < 10; ++j) s += features[b * 10 + j] * fc0_w[i * 10 + j];
        const float a = a0[0];
        h0[b][i] = (s >= 0.f) ? s : a * s;
    }
    __syncthreads();
    if (t < 64) {
        const int b = t >> 3, i = t & 7;
        float s = fc1_b[i];
        #pragma unroll
        for (int j = 0; j < 16; ++j) s += h0[b][j] * fc1_w[i * 16 + j];
        const float a = a1[0];
        const float r = (s >= 0.f) ? s : a * s;
        h1s[b][i] = r;
        h1out[b * 8 + i] = r;
    }
    __syncthreads();
    {   // biases: 256 threads = 8 b x 32 co
        const int b = t >> 5, co = t & 31;
        const int p = NUM_W + co;
        float s = wg_b[p];
        #pragma unroll
        for (int j = 0; j < 8; ++j) s += h1s[b][j] * wg_w[p * 8 + j];
        biasout[b * 32 + co] = s;
    }
}

// A in FRAGMENT order: AF[b][c][mt][lane][8 shorts], where lane = qs*16+nn
// holds co = mt*16+nn, k = c*32 + qs*8 .. +7  (k = tap*16+ci, tap=kd*9+kh*3+kw).
// tap = 2c + (qs>=2); ci = (qs&1)*8 + j. tap==27 chunks are zeros.
__global__ void wgen_kernel(const float* __restrict__ h1,
                            const float* __restrict__ wg_w,
                            const float* __restrict__ wg_b,
                            short* __restrict__ A) {
    const int b  = blockIdx.y;
    const int id = blockIdx.x * 256 + threadIdx.x;  // [0, 32*16*28)
    const int tap  = id % 28;
    const int rest = id / 28;        // co*16 + ci
    const int ci   = rest & 15;
    const int co   = rest >> 4;
    float val = 0.f;
    if (tap < 27) {
        const int p = co * 432 + ci * 27 + tap;
        float s = wg_b[p];
        #pragma unroll
        for (int j = 0; j < 8; ++j) s += h1[b * 8 + j] * wg_w[p * 8 + j];
        val = s;
    }
    const int c    = tap >> 1;               // 0..13
    const int qs   = (tap & 1) * 2 + (ci >> 3);
    const int nn   = co & 15;
    const int mt   = co >> 4;
    const int lane = qs * 16 + nn;
    A[((((size_t)b * 14 + c) * 2 + mt) * 64 + lane) * 8 + (ci & 7)] = f2bf(val);
}

// Implicit-GEMM conv via MFMA 16x16x32 bf16 — persistent 8-tile blocks.
// Block = 256 thr = 4 waves; fixes (b, d, h-half); loops 8 tiles over h0.
// A (fragment-order) staged to LDS ONCE per block via a linear coalesced
// copy; K-loop A-reads are the canonical conflict-free lane*16 pattern.
// x-patch is a ROLLING hz-window (slot = (zh+1) mod 6): tiles 1..7 stage
// only 12 new rows, loads batched 3-rows-deep for latency overlap.
__global__ __launch_bounds__(256, 2) void conv_mfma_kernel(
        const float* __restrict__ x,
        const short* __restrict__ A,
        const float* __restrict__ bias,
        float* __restrict__ out) {
    __shared__ uint4 xs4[2376];            // 38016 B: [dz 3][slot 6][wz 66][ci 16]
    __shared__ uint4 als4[1664];           // 26624 B = chunks (c 0..12) x (mt) x 64
    char* xsb = (char*)xs4;
    char* alb = (char*)als4;

    const int t    = threadIdx.x;
    const int lane = t & 63;
    const int wave = t >> 6;
    const int n16  = lane & 15;
    const int q    = lane >> 4;

    // Persistent grid: 1024 blocks, 8 XCDs -> each XCD owns one sample b.
    const int lin   = blockIdx.x;                    // 0..1023
    const int o     = (lin & 7) * 128 + (lin >> 3);  // bijective
    const int b     = o >> 7;                        // 0..7
    const int rest  = o & 127;
    const int d     = rest >> 1;                     // 0..63
    const int hbase = (rest & 1) * 32;               // h0 = hbase + it*4

    const uint4* AFb = (const uint4*)A + (size_t)b * 1792;   // 14*2*64 chunks

    // ---- stage A chunks c0..12 -> LDS once: LINEAR coalesced copy ----
    #pragma unroll
    for (int i = 0; i < 7; ++i) {
        const int u = t + i * 256;
        if (u < 1664) als4[u] = AFb[u];
    }

    // ---- chunk c13 (taps 26,27; tap-27 half is zeros) per-thread regs ----
    short8 af13[2];
    af13[0] = *(const short8*)(AFb + 26 * 64 + lane);
    af13[1] = *(const short8*)(AFb + 27 * 64 + lane);

    // ---- zero the w-halo columns (wz=0,65) once; staging never writes them ----
    if (t < 72) {
        const int rowl = t >> 2;                 // 0..17
        const int wz   = ((t >> 1) & 1) * 65;    // 0 or 65
        const int half = t & 1;
        const uint4 z4 = {0u, 0u, 0u, 0u};
        *(uint4*)(xsb + swz((rowl * 66 + wz) * 32 + half * 16)) = z4;
    }

    const float bv0 = bias[b * 32 + n16];
    const float bv1 = bias[b * 32 + 16 + n16];

    // staging thread map: (ci-pair cp, row-half rhalf)
    const int tid16 = wave * 4 + q;      // 0..15
    const int cp    = tid16 & 7;         // ci = 2*cp, 2*cp+1
    const int rhalf = tid16 >> 3;        // 0/1
    const int w4    = n16 * 4;

    const int ci_base2 = (q & 1) * 16;   // byte offset of ci half
    const int qh       = q >> 1;
    const int aoff     = lane * 16;      // conflict-free linear A-read

    #pragma unroll 1
    for (int it = 0; it < 8; ++it) {
        const int h0 = hbase + it * 4;
        const int p  = h0 % 6;           // phys slot = (p + hz) mod 6 = (zh+1) mod 6

        __syncthreads();   // prev tile's LDS reads (or A-stage/halo-zero) done

        if (it == 0) {
            // full window: 18 rows, 9 per rhalf, 3-row batches
            #pragma unroll
            for (int bt = 0; bt < 3; ++bt) {
                float4 va[3], vb[3];
                int rbs[3];
                #pragma unroll
                for (int j = 0; j < 3; ++j) {
                    const int rowl = rhalf * 9 + bt * 3 + j;   // dz*6+hz
                    const int dz = rowl / 6, hz = rowl % 6;
                    int phys = p + hz; if (phys >= 6) phys -= 6;
                    const int zd = d + dz - 1, zh = h0 + hz - 1;
                    va[j] = (float4){0.f, 0.f, 0.f, 0.f};
                    vb[j] = (float4){0.f, 0.f, 0.f, 0.f};
                    if (zd >= 0 && zd < DD && zh >= 0 && zh < DD) {  // wave-uniform
                        const size_t gbase =
                            (((size_t)(b * CIN + 2 * cp) * DD + zd) * DD + zh) * DD + w4;
                        va[j] = *(const float4*)(x + gbase);
                        vb[j] = *(const float4*)(x + gbase + (size_t)DD * DD * DD);
                    }
                    rbs[j] = ((dz * 6 + phys) * 66 + (w4 + 1)) * 32 + 4 * cp;
                }
                #pragma unroll
                for (int j = 0; j < 3; ++j) {
                    *(unsigned*)(xsb + swz(rbs[j]))      = pack2bf(va[j].x, vb[j].x);
                    *(unsigned*)(xsb + swz(rbs[j] + 32)) = pack2bf(va[j].y, vb[j].y);
                    *(unsigned*)(xsb + swz(rbs[j] + 64)) = pack2bf(va[j].z, vb[j].z);
                    *(unsigned*)(xsb + swz(rbs[j] + 96)) = pack2bf(va[j].w, vb[j].w);
                }
            }
        } else {
            // rolling: only hz 2..5 are new (zh = h0+1 .. h0+4), 12 rows
            #pragma unroll
            for (int bt = 0; bt < 2; ++bt) {
                float4 va[3], vb[3];
                int rbs[3];
                #pragma unroll
                for (int j = 0; j < 3; ++j) {
                    const int idx = rhalf * 6 + bt * 3 + j;    // 0..11
                    const int dz = idx >> 2, jj = idx & 3;     // hz = 2+jj
                    int phys = p + 2 + jj; if (phys >= 6) phys -= 6;
                    const int zd = d + dz - 1, zh = h0 + 1 + jj;
                    va[j] = (float4){0.f, 0.f, 0.f, 0.f};
                    vb[j] = (float4){0.f, 0.f, 0.f, 0.f};
                    if (zd >= 0 && zd < DD) {                  // wave-uniform (zh<64 can fail only at zh=64)
                        if (zh < DD) {
                            const size_t gbase =
                                (((size_t)(b * CIN + 2 * cp) * DD + zd) * DD + zh) * DD + w4;
                            va[j] = *(const float4*)(x + gbase);
                            vb[j] = *(const float4*)(x + gbase + (size_t)DD * DD * DD);
                        }
                    }
                    rbs[j] = ((dz * 6 + phys) * 66 + (w4 + 1)) * 32 + 4 * cp;
                }
                #pragma unroll
                for (int j = 0; j < 3; ++j) {
                    *(unsigned*)(xsb + swz(rbs[j]))      = pack2bf(va[j].x, vb[j].x);
                    *(unsigned*)(xsb + swz(rbs[j] + 32)) = pack2bf(va[j].y, vb[j].y);
                    *(unsigned*)(xsb + swz(rbs[j] + 64)) = pack2bf(va[j].z, vb[j].z);
                    *(unsigned*)(xsb + swz(rbs[j] + 96)) = pack2bf(va[j].w, vb[j].w);
                }
            }
        }
        __syncthreads();

        // ---- K-loop: operand-swapped MFMA (x in A slot, weights in B slot) ----
        floatx4 acc[2][4];
        #pragma unroll
        for (int mt = 0; mt < 2; ++mt)
            #pragma unroll
            for (int nt = 0; nt < 4; ++nt) acc[mt][nt] = (floatx4){0.f, 0.f, 0.f, 0.f};

        __builtin_amdgcn_s_setprio(1);
        #pragma unroll
        for (int c = 0; c < 14; ++c) {
            int tap = 2 * c + qh;
            if (tap > 26) tap = 26;        // A zero for k>=432, x value irrelevant
            const int kd = tap / 9;
            const int r  = tap - kd * 9;
            const int kh = r / 3;
            const int kw = r - kh * 3;
            int prow = p + wave + kh; if (prow >= 6) prow -= 6;
            const int rowb = ((kd * 6 + prow) * 66 + kw) * 32 + ci_base2;
            const short8 a0 = (c < 13) ? *(const short8*)(alb + (c * 2) * 1024 + aoff)
                                       : af13[0];
            const short8 a1 = (c < 13) ? *(const short8*)(alb + (c * 2 + 1) * 1024 + aoff)
                                       : af13[1];
            #pragma unroll
            for (int nt = 0; nt < 4; ++nt) {
                const short8 xf = *(const short8*)(xsb + swz(rowb + (nt * 16 + n16) * 32));
                acc[0][nt] = __builtin_amdgcn_mfma_f32_16x16x32_bf16(
                                 xf, a0, acc[0][nt], 0, 0, 0);
                acc[1][nt] = __builtin_amdgcn_mfma_f32_16x16x32_bf16(
                                 xf, a1, acc[1][nt], 0, 0, 0);
            }
        }
        __builtin_amdgcn_s_setprio(0);

        // ---- epilogue: row=w=nt*16+q*4+reg, col=co=mt*16+n16 -> float4 stores ----
        const int hh = h0 + wave;
        #pragma unroll
        for (int mt = 0; mt < 2; ++mt) {
            const float bv = mt ? bv1 : bv0;
            #pragma unroll
            for (int nt = 0; nt < 4; ++nt) {
                floatx4 rr = acc[mt][nt];
                rr[0] += bv; rr[1] += bv; rr[2] += bv; rr[3] += bv;
                *(floatx4*)(out + (((size_t)(b * COUT + mt * 16 + n16) * DD + d) * DD + hh) * DD
                                 + nt * 16 + q * 4) = rr;
            }
        }
    }
}

extern "C" void kernel_launch(void* const* d_in, const int* in_sizes, int n_in,
                              void* d_out, int out_size, void* d_ws, size_t ws_size,
                              hipStream_t stream) {
    const float* x        = (const float*)d_in[0];
    const float* features = (const float*)d_in[1];
    const float* fc0_w    = (const float*)d_in[2];
    const float* fc0_b    = (const float*)d_in[3];
    const float* a0       = (const float*)d_in[4];
    const float* fc1_w    = (const float*)d_in[5];
    const float* fc1_b    = (const float*)d_in[6];
    const float* a1       = (const float*)d_in[7];
    const float* wg_w     = (const float*)d_in[8];
    const float* wg_b     = (const float*)d_in[9];

    float* ws    = (float*)d_ws;
    float* h1    = ws;                // 64 floats
    float* biasp = ws + 64;           // 256 floats
    short* A     = (short*)(ws + 320);  // fragment-order A, 229376 B

    hyper_kernel<<<1, 256, 0, stream>>>(features, fc0_w, fc0_b, a0,
                                        fc1_w, fc1_b, a1, wg_w, wg_b, h1, biasp);
    wgen_kernel<<<dim3(56, BB), 256, 0, stream>>>(h1, wg_w, wg_b, A);
    conv_mfma_kernel<<<dim3(1024), 256, 0, stream>>>(x, A, biasp, (float*)d_out);
}

// Round 9
// 422.942 us; speedup vs baseline: 1.1035x; 1.0088x over previous
//
#include <hip/hip_runtime.h>

typedef short short8 __attribute__((ext_vector_type(8)));
typedef float floatx4 __attribute__((ext_vector_type(4)));

#define BB   8
#define CIN  16
#define COUT 32
#define DD   64
#define NUM_W (CIN * COUT * 27)   // 13824
#define NUM_P (NUM_W + COUT)      // 13856

// ws layout (floats): [0,64) h1 (8x8); [64,320) bias (8x32);
// [320, ...) A fragment-order bf16: AF[b][c 14][mt 2][lane 64][8 shorts]
//            = 8 * 14*2*64*8 shorts = 229376 B. Total ~231 KB.

__device__ __forceinline__ short f2bf(float f) {
    union { float f; unsigned u; } v; v.f = f;
    unsigned r = v.u + 0x7FFF + ((v.u >> 16) & 1);   // RNE
    return (short)(r >> 16);
}

// pack bf16(lo) | bf16(hi)<<16, both RNE — identical numerics to f2bf
__device__ __forceinline__ unsigned pack2bf(float lo, float hi) {
    union { float f; unsigned u; } a, b; a.f = lo; b.f = hi;
    unsigned ra = a.u + 0x7FFF + ((a.u >> 16) & 1);
    unsigned rb = b.u + 0x7FFF + ((b.u >> 16) & 1);
    return (ra >> 16) | (rb & 0xFFFF0000u);
}

// LDS bank-conflict swizzle for the x-patch: XOR bits 4-6 with bits 7-9.
// Bijective per 128B window (xs = 50688 B = 396 * 128B exactly).
__device__ __forceinline__ int swz(int byte) {
    return byte ^ (((byte >> 7) & 7) << 4);
}

__global__ void hyper_kernel(const float* __restrict__ features,
                             const float* __restrict__ fc0_w,
                             const float* __restrict__ fc0_b,
                             const float* __restrict__ a0,
                             const float* __restrict__ fc1_w,
                             const float* __restrict__ fc1_b,
                             const float* __restrict__ a1,
                             const float* __restrict__ wg_w,
                             const float* __restrict__ wg_b,
                             float* __restrict__ h1out,
                             float* __restrict__ biasout) {
    __shared__ float h0[8][16];
    __shared__ float h1s[8][8];
    const int t = threadIdx.x;  // 256
    if (t < 128) {
        const int b = t >> 4, i = t & 15;
        float s = fc0_b[i];
        #pragma unroll
        for (int j = 0; j < 10; ++j) s += features[b * 10 + j] * fc0_w[i * 10 + j];
        const float a = a0[0];
        h0[b][i] = (s >= 0.f) ? s : a * s;
    }
    __syncthreads();
    if (t < 64) {
        const int b = t >> 3, i = t & 7;
        float s = fc1_b[i];
        #pragma unroll
        for (int j = 0; j < 16; ++j) s += h0[b][j] * fc1_w[i * 16 + j];
        const float a = a1[0];
        const float r = (s >= 0.f) ? s : a * s;
        h1s[b][i] = r;
        h1out[b * 8 + i] = r;
    }
    __syncthreads();
    {   // biases: 256 threads = 8 b x 32 co
        const int b = t >> 5, co = t & 31;
        const int p = NUM_W + co;
        float s = wg_b[p];
        #pragma unroll
        for (int j = 0; j < 8; ++j) s += h1s[b][j] * wg_w[p * 8 + j];
        biasout[b * 32 + co] = s;
    }
}

// A in FRAGMENT order: AF[b][c][mt][lane][8 shorts], where lane = qs*16+nn
// holds co = mt*16+nn, k = c*32 + qs*8 .. +7  (k = tap*16+ci, tap=kd*9+kh*3+kw).
// tap = 2c + (qs>=2); ci = (qs&1)*8 + j. tap==27 chunks are zeros.
__global__ void wgen_kernel(const float* __restrict__ h1,
                            const float* __restrict__ wg_w,
                            const float* __restrict__ wg_b,
                            short* __restrict__ A) {
    const int b  = blockIdx.y;
    const int id = blockIdx.x * 256 + threadIdx.x;  // [0, 32*16*28)
    const int tap  = id % 28;
    const int rest = id / 28;        // co*16 + ci
    const int ci   = rest & 15;
    const int co   = rest >> 4;
    float val = 0.f;
    if (tap < 27) {
        const int p = co * 432 + ci * 27 + tap;
        float s = wg_b[p];
        #pragma unroll
        for (int j = 0; j < 8; ++j) s += h1[b * 8 + j] * wg_w[p * 8 + j];
        val = s;
    }
    const int c    = tap >> 1;               // 0..13
    const int qs   = (tap & 1) * 2 + (ci >> 3);
    const int nn   = co & 15;
    const int mt   = co >> 4;
    const int lane = qs * 16 + nn;
    A[((((size_t)b * 14 + c) * 2 + mt) * 64 + lane) * 8 + (ci & 7)] = f2bf(val);
}

// Implicit-GEMM conv via MFMA 16x16x32 bf16 — d-PAIRED persistent blocks.
// 512 blocks = exactly 2/CU; block = 4 waves; fixes (b, d-pair, h-half);
// loops 8 h-tiles. Per tile-iter: stage ONE 4-dz rolling window, run TWO
// K-loops (dd=0,1 use dz dd..dd+2) -> staging amortized over 2 output
// planes (global d-redundancy 3x -> 2x). A fragment-order in LDS (linear
// copy, conflict-free lane*16 reads). LDS = 50.7 + 26.6 = 77.3 KB.
__global__ __launch_bounds__(256, 2) void conv_mfma_kernel(
        const float* __restrict__ x,
        const short* __restrict__ A,
        const float* __restrict__ bias,
        float* __restrict__ out) {
    __shared__ uint4 xs4[3168];            // 50688 B: [dz 4][slot 6][wz 66][ci 16]
    __shared__ uint4 als4[1664];           // 26624 B: chunks (c 0..12) x (mt) x 64
    char* xsb = (char*)xs4;
    char* alb = (char*)als4;

    const int t    = threadIdx.x;
    const int lane = t & 63;
    const int wave = t >> 6;
    const int n16  = lane & 15;
    const int q    = lane >> 4;

    // 512 blocks, 8 XCDs -> 64 blocks/XCD = one sample b per XCD.
    const int lin   = blockIdx.x;                    // 0..511
    const int o     = (lin & 7) * 64 + (lin >> 3);   // bijective
    const int b     = o >> 6;                        // 0..7
    const int rest  = o & 63;
    const int d     = (rest >> 1) * 2;               // 0,2,..,62 (d-pair base)
    const int hbase = (rest & 1) * 32;               // h0 = hbase + it*4

    const uint4* AFb = (const uint4*)A + (size_t)b * 1792;   // 14*2*64 chunks

    // ---- stage A chunks c0..12 -> LDS once: LINEAR coalesced copy ----
    #pragma unroll
    for (int i = 0; i < 7; ++i) {
        const int u = t + i * 256;
        if (u < 1664) als4[u] = AFb[u];
    }

    // ---- chunk c13 (taps 26,27; tap-27 half is zeros) per-thread regs ----
    short8 af13[2];
    af13[0] = *(const short8*)(AFb + 26 * 64 + lane);
    af13[1] = *(const short8*)(AFb + 27 * 64 + lane);

    // ---- zero the w-halo columns (wz=0,65) once; staging never writes them ----
    if (t < 96) {
        const int rowl = t >> 2;                 // 0..23 = dz*6+slot
        const int wz   = ((t >> 1) & 1) * 65;    // 0 or 65
        const int half = t & 1;
        const uint4 z4 = {0u, 0u, 0u, 0u};
        *(uint4*)(xsb + swz((rowl * 66 + wz) * 32 + half * 16)) = z4;
    }

    const float bv0 = bias[b * 32 + n16];
    const float bv1 = bias[b * 32 + 16 + n16];

    // staging thread map: (ci-pair cp, row-half rhalf); rhalf wave-uniform
    const int tid16 = wave * 4 + q;      // 0..15
    const int cp    = tid16 & 7;         // ci = 2*cp, 2*cp+1
    const int rhalf = tid16 >> 3;        // 0/1 (waves 0,1 / 2,3)
    const int w4    = n16 * 4;

    const int ci_base2 = (q & 1) * 16;   // byte offset of ci half
    const int qh       = q >> 1;
    const int aoff     = lane * 16;      // conflict-free linear A-read

    #pragma unroll 1
    for (int it = 0; it < 8; ++it) {
        const int h0 = hbase + it * 4;
        const int p  = h0 % 6;           // phys slot = (p + hz) mod 6 = (zh+1) mod 6

        __syncthreads();   // prev tile's LDS reads (or A-stage/halo-zero) done

        if (it == 0) {
            // full window: 4 dz x 6 hz = 24 rows, 12 per rhalf, 4-row batches
            #pragma unroll
            for (int bt = 0; bt < 3; ++bt) {
                float4 va[4], vb[4];
                int rbs[4];
                #pragma unroll
                for (int j = 0; j < 4; ++j) {
                    const int rowl = rhalf * 12 + bt * 4 + j;   // dz*6+hz
                    const int dz = rowl / 6, hz = rowl % 6;
                    int phys = p + hz; if (phys >= 6) phys -= 6;
                    const int zd = d + dz - 1, zh = h0 + hz - 1;
                    va[j] = (float4){0.f, 0.f, 0.f, 0.f};
                    vb[j] = (float4){0.f, 0.f, 0.f, 0.f};
                    if (zd >= 0 && zd < DD && zh >= 0 && zh < DD) {  // wave-uniform
                        const size_t gbase =
                            (((size_t)(b * CIN + 2 * cp) * DD + zd) * DD + zh) * DD + w4;
                        va[j] = *(const float4*)(x + gbase);
                        vb[j] = *(const float4*)(x + gbase + (size_t)DD * DD * DD);
                    }
                    rbs[j] = ((dz * 6 + phys) * 66 + (w4 + 1)) * 32 + 4 * cp;
                }
                #pragma unroll
                for (int j = 0; j < 4; ++j) {
                    *(unsigned*)(xsb + swz(rbs[j]))      = pack2bf(va[j].x, vb[j].x);
                    *(unsigned*)(xsb + swz(rbs[j] + 32)) = pack2bf(va[j].y, vb[j].y);
                    *(unsigned*)(xsb + swz(rbs[j] + 64)) = pack2bf(va[j].z, vb[j].z);
                    *(unsigned*)(xsb + swz(rbs[j] + 96)) = pack2bf(va[j].w, vb[j].w);
                }
            }
        } else {
            // rolling: hz 2..5 new (zh = h0+1 .. h0+4) x 4 dz = 16 rows, 8/rhalf
            #pragma unroll
            for (int bt = 0; bt < 2; ++bt) {
                float4 va[4], vb[4];
                int rbs[4];
                #pragma unroll
                for (int j = 0; j < 4; ++j) {
                    const int idx = rhalf * 8 + bt * 4 + j;    // 0..15
                    const int dz = idx >> 2, jj = idx & 3;     // hz = 2+jj
                    int phys = p + 2 + jj; if (phys >= 6) phys -= 6;
                    const int zd = d + dz - 1, zh = h0 + 1 + jj;
                    va[j] = (float4){0.f, 0.f, 0.f, 0.f};
                    vb[j] = (float4){0.f, 0.f, 0.f, 0.f};
                    if (zd >= 0 && zd < DD && zh < DD) {       // wave-uniform
                        const size_t gbase =
                            (((size_t)(b * CIN + 2 * cp) * DD + zd) * DD + zh) * DD + w4;
                        va[j] = *(const float4*)(x + gbase);
                        vb[j] = *(const float4*)(x + gbase + (size_t)DD * DD * DD);
                    }
                    rbs[j] = ((dz * 6 + phys) * 66 + (w4 + 1)) * 32 + 4 * cp;
                }
                #pragma unroll
                for (int j = 0; j < 4; ++j) {
                    *(unsigned*)(xsb + swz(rbs[j]))      = pack2bf(va[j].x, vb[j].x);
                    *(unsigned*)(xsb + swz(rbs[j] + 32)) = pack2bf(va[j].y, vb[j].y);
                    *(unsigned*)(xsb + swz(rbs[j] + 64)) = pack2bf(va[j].z, vb[j].z);
                    *(unsigned*)(xsb + swz(rbs[j] + 96)) = pack2bf(va[j].w, vb[j].w);
                }
            }
        }
        __syncthreads();

        // ---- TWO K-loops per staged window: dd = 0,1 use dz dd..dd+2 ----
        #pragma unroll 1
        for (int dd = 0; dd < 2; ++dd) {
            floatx4 acc[2][4];
            #pragma unroll
            for (int mt = 0; mt < 2; ++mt)
                #pragma unroll
                for (int nt = 0; nt < 4; ++nt) acc[mt][nt] = (floatx4){0.f, 0.f, 0.f, 0.f};

            __builtin_amdgcn_s_setprio(1);
            #pragma unroll
            for (int c = 0; c < 14; ++c) {
                int tap = 2 * c + qh;
                if (tap > 26) tap = 26;        // A zero for k>=432, x value irrelevant
                const int kd = tap / 9;
                const int r  = tap - kd * 9;
                const int kh = r / 3;
                const int kw = r - kh * 3;
                int prow = p + wave + kh; if (prow >= 6) prow -= 6;
                const int rowb = (((kd + dd) * 6 + prow) * 66 + kw) * 32 + ci_base2;
                const short8 a0 = (c < 13) ? *(const short8*)(alb + (c * 2) * 1024 + aoff)
                                           : af13[0];
                const short8 a1 = (c < 13) ? *(const short8*)(alb + (c * 2 + 1) * 1024 + aoff)
                                           : af13[1];
                #pragma unroll
                for (int nt = 0; nt < 4; ++nt) {
                    const short8 xf = *(const short8*)(xsb + swz(rowb + (nt * 16 + n16) * 32));
                    acc[0][nt] = __builtin_amdgcn_mfma_f32_16x16x32_bf16(
                                     xf, a0, acc[0][nt], 0, 0, 0);
                    acc[1][nt] = __builtin_amdgcn_mfma_f32_16x16x32_bf16(
                                     xf, a1, acc[1][nt], 0, 0, 0);
                }
            }
            __builtin_amdgcn_s_setprio(0);

            // epilogue: row=w=nt*16+q*4+reg, col=co=mt*16+n16 -> float4 stores
            const int hh = h0 + wave;
            #pragma unroll
            for (int mt = 0; mt < 2; ++mt) {
                const float bv = mt ? bv1 : bv0;
                #pragma unroll
                for (int nt = 0; nt < 4; ++nt) {
                    floatx4 rr = acc[mt][nt];
                    rr[0] += bv; rr[1] += bv; rr[2] += bv; rr[3] += bv;
                    *(floatx4*)(out + (((size_t)(b * COUT + mt * 16 + n16) * DD + (d + dd)) * DD + hh) * DD
                                     + nt * 16 + q * 4) = rr;
                }
            }
        }
    }
}

extern "C" void kernel_launch(void* const* d_in, const int* in_sizes, int n_in,
                              void* d_out, int out_size, void* d_ws, size_t ws_size,
                              hipStream_t stream) {
    const float* x        = (const float*)d_in[0];
    const float* features = (const float*)d_in[1];
    const float* fc0_w    = (const float*)d_in[2];
    const float* fc0_b    = (const float*)d_in[3];
    const float* a0       = (const float*)d_in[4];
    const float* fc1_w    = (const float*)d_in[5];
    const float* fc1_b    = (const float*)d_in[6];
    const float* a1       = (const float*)d_in[7];
    const float* wg_w     = (const float*)d_in[8];
    const float* wg_b     = (const float*)d_in[9];

    float* ws    = (float*)d_ws;
    float* h1    = ws;                // 64 floats
    float* biasp = ws + 64;           // 256 floats
    short* A     = (short*)(ws + 320);  // fragment-order A, 229376 B

    hyper_kernel<<<1, 256, 0, stream>>>(features, fc0_w, fc0_b, a0,
                                        fc1_w, fc1_b, a1, wg_w, wg_b, h1, biasp);
    wgen_kernel<<<dim3(56, BB), 256, 0, stream>>>(h1, wg_w, wg_b, A);
    conv_mfma_kernel<<<dim3(512), 256, 0, stream>>>(x, A, biasp, (float*)d_out);
}